// Round 3
// baseline (1410.338 us; speedup 1.0000x reference)
//
#include <hip/hip_runtime.h>

#define NPTS 2048
#define CPL  32            // columns per lane (2048 / 64)
#define HCPL 16            // column pairs per lane

typedef float v2f __attribute__((ext_vector_type(2)));
typedef unsigned long long u64;

static __device__ __forceinline__ u64 umin64(u64 a, u64 b) { return b < a ? b : a; }

// xor-style butterfly step via DPP (lanes pair within 16-lane rows).
template <int CTRL>
static __device__ __forceinline__ u64 dpp_min(u64 k) {
  unsigned lo = (unsigned)k, hi = (unsigned)(k >> 32);
  unsigned olo = (unsigned)__builtin_amdgcn_mov_dpp((int)lo, CTRL, 0xF, 0xF, true);
  unsigned ohi = (unsigned)__builtin_amdgcn_mov_dpp((int)hi, CTRL, 0xF, 0xF, true);
  return umin64(k, ((u64)ohi << 32) | olo);
}

// lane ^ 16 exchange, VALU-only on gfx950.
static __device__ __forceinline__ u64 x16_min(u64 k) {
  unsigned lo = (unsigned)k, hi = (unsigned)(k >> 32);
#if __has_builtin(__builtin_amdgcn_permlane16_swap)
  auto rlo = __builtin_amdgcn_permlane16_swap(lo, lo, false, false);
  auto rhi = __builtin_amdgcn_permlane16_swap(hi, hi, false, false);
  u64 a = ((u64)rhi[0] << 32) | rlo[0];
  u64 b = ((u64)rhi[1] << 32) | rlo[1];
  return umin64(k, umin64(a, b));
#else
  unsigned olo = (unsigned)__builtin_amdgcn_ds_swizzle((int)lo, 0x401F);
  unsigned ohi = (unsigned)__builtin_amdgcn_ds_swizzle((int)hi, 0x401F);
  return umin64(k, ((u64)ohi << 32) | olo);
#endif
}

// lane ^ 32 exchange, VALU-only on gfx950.
static __device__ __forceinline__ u64 x32_min(u64 k) {
  unsigned lo = (unsigned)k, hi = (unsigned)(k >> 32);
#if __has_builtin(__builtin_amdgcn_permlane32_swap)
  auto rlo = __builtin_amdgcn_permlane32_swap(lo, lo, false, false);
  auto rhi = __builtin_amdgcn_permlane32_swap(hi, hi, false, false);
  u64 a = ((u64)rhi[0] << 32) | rlo[0];
  u64 b = ((u64)rhi[1] << 32) | rlo[1];
  return umin64(k, umin64(a, b));
#else
  unsigned olo = (unsigned)__shfl_xor((int)lo, 32, 64);
  unsigned ohi = (unsigned)__shfl_xor((int)hi, 32, 64);
  return umin64(k, ((u64)ohi << 32) | olo);
#endif
}

// One wave per batch; 8 independent blocks. Lane L owns columns
// j = L*32 .. L*32+31 in registers. Per row: packed-fp32 distance eval ->
// u64 (d2bits<<32 | localk) key tournament tree -> all-VALU wave min
// (DPP + permlane swaps, zero DS ops) -> branchless usedmask update.
__global__ __launch_bounds__(64, 1) void emd_greedy_kernel(
    const float* __restrict__ pred, const float* __restrict__ target,
    float* __restrict__ batch_sums) {
  const int b    = blockIdx.x;
  const int lane = threadIdx.x;
  const float* p = pred   + (size_t)b * NPTS * 3;
  const float* t = target + (size_t)b * NPTS * 3;

  // Pred point + squared norm, packed for one ds_read_b128 per row.
  __shared__ float4 pp[NPTS + 2];
  for (int i = lane; i < NPTS; i += 64) {
    float x = p[3 * i + 0], y = p[3 * i + 1], z = p[3 * i + 2];
    pp[i] = make_float4(x, y, z, x * x + y * y + z * z);
  }
  if (lane < 2) pp[NPTS + lane] = make_float4(0.f, 0.f, 0.f, 0.f);

  // Own target columns (contiguous per lane) in registers, as float2 pairs.
  v2f TX[HCPL], TY[HCPL], TZ[HCPL], TQ[HCPL];
  const float* tb = t + (size_t)lane * CPL * 3;
#pragma unroll
  for (int h = 0; h < HCPL; ++h) {
    float x0 = tb[6 * h + 0], y0 = tb[6 * h + 1], z0 = tb[6 * h + 2];
    float x1 = tb[6 * h + 3], y1 = tb[6 * h + 4], z1 = tb[6 * h + 5];
    TX[h] = (v2f){x0, x1};
    TY[h] = (v2f){y0, y1};
    TZ[h] = (v2f){z0, z1};
    TQ[h] = (v2f){x0 * x0 + y0 * y0 + z0 * z0,
                  x1 * x1 + y1 * y1 + z1 * z1};
  }
  unsigned usedmask = 0;  // bit k set => column lane*32+k consumed
  float sum = 0.f;
  __syncthreads();

  const v2f m2v  = {-2.f, -2.f};
  const v2f epsv = {1e-12f, 1e-12f};
  float4 cur = pp[0];

  for (int i = 0; i < NPTS; ++i) {
    float4 nxt = pp[i + 1];  // single DS op per row, hidden under the body

    const v2f Xv = {cur.x, cur.x}, Yv = {cur.y, cur.y}, Zv = {cur.z, cur.z};
    const v2f Qv = {cur.w, cur.w};

    // 4 parallel tournament chains over 16 pair-keys (depth ~6 total).
    u64 c0 = ~0ULL, c1 = ~0ULL, c2 = ~0ULL, c3 = ~0ULL;
    u64 ch[4] = {c0, c1, c2, c3};
#pragma unroll
    for (int h = 0; h < HCPL; ++h) {
      // Exact ref arithmetic: d2 = clamp(Q + fma(-2, dot, tq), 1e-12)
#if __has_builtin(__builtin_elementwise_fma)
      v2f dot = __builtin_elementwise_fma(
          TX[h], Xv, __builtin_elementwise_fma(TY[h], Yv, TZ[h] * Zv));
      v2f dd  = __builtin_elementwise_fma(m2v, dot, TQ[h]);
#else
      v2f dot = {fmaf(TX[h].x, Xv.x, fmaf(TY[h].x, Yv.x, TZ[h].x * Zv.x)),
                 fmaf(TX[h].y, Xv.y, fmaf(TY[h].y, Yv.y, TZ[h].y * Zv.y))};
      v2f dd  = {fmaf(m2v.x, dot.x, TQ[h].x), fmaf(m2v.y, dot.y, TQ[h].y)};
#endif
      v2f d2 = Qv + dd;
      v2f cl = {fmaxf(d2.x, epsv.x), fmaxf(d2.y, epsv.y)};  // pk_max
      // Positive-float bits order as u32; used column -> 0xFFFFFFFF.
      unsigned e0 = (unsigned)(((int)(usedmask << (31 - (2 * h + 0)))) >> 31);
      unsigned e1 = (unsigned)(((int)(usedmask << (31 - (2 * h + 1)))) >> 31);
      unsigned u0 = (unsigned)__float_as_int(cl.x) | e0;
      unsigned u1 = (unsigned)__float_as_int(cl.y) | e1;
      bool tsel = u1 < u0;  // strict: keeps smaller index on exact ties
      unsigned pu = tsel ? u1 : u0;
      unsigned pk = tsel ? (unsigned)(2 * h + 1) : (unsigned)(2 * h);
      u64 key = ((u64)pu << 32) | pk;
      ch[h & 3] = umin64(ch[h & 3], key);  // static index under full unroll
    }
    u64 k = umin64(umin64(ch[0], ch[1]), umin64(ch[2], ch[3]));
    // Attach lane to the index: global j = lane*32 + k5.
    k |= (u64)((unsigned)lane << 5);

    // All-VALU wave-wide u64 min (smallest j wins ties).
    k = dpp_min<0xB1>(k);   // xor 1  (quad_perm 1,0,3,2)
    k = dpp_min<0x4E>(k);   // xor 2  (quad_perm 2,3,0,1)
    k = dpp_min<0x141>(k);  // pair within half-row (row_half_mirror)
    k = dpp_min<0x140>(k);  // pair within row (row_mirror)
    k = x16_min(k);         // lane ^ 16
    k = x32_min(k);         // lane ^ 32

    const unsigned j  = (unsigned)k & 0x7FFu;
    const unsigned mu = (unsigned)(k >> 32);
    // Branchless: winning lane flips its own column bit.
    usedmask |= (lane == (int)(j >> 5)) ? (1u << (j & 31u)) : 0u;
    sum += sqrtf(__uint_as_float(mu));  // mu already clamped
    cur = nxt;
  }
  if (lane == 0) batch_sums[b] = sum;
}

// mean over batches of (per-batch sum / N)
__global__ void emd_finalize_kernel(const float* __restrict__ batch_sums,
                                    float* __restrict__ out, int B) {
  float acc = 0.f;
  for (int b = 0; b < B; ++b) acc += batch_sums[b] / (float)NPTS;
  out[0] = acc / (float)B;
}

extern "C" void kernel_launch(void* const* d_in, const int* in_sizes, int n_in,
                              void* d_out, int out_size, void* d_ws, size_t ws_size,
                              hipStream_t stream) {
  const float* pred   = (const float*)d_in[0];
  const float* target = (const float*)d_in[1];
  float* ws  = (float*)d_ws;
  float* out = (float*)d_out;
  const int B = in_sizes[0] / (NPTS * 3);

  emd_greedy_kernel<<<B, 64, 0, stream>>>(pred, target, ws);
  emd_finalize_kernel<<<1, 1, 0, stream>>>(ws, out, B);
}

// Round 4
// 1160.104 us; speedup vs baseline: 1.2157x; 1.2157x over previous
//
#include <hip/hip_runtime.h>

#define NPTS 2048

typedef float v2f __attribute__((ext_vector_type(2)));
typedef unsigned int u32;
typedef u32 v2u __attribute__((ext_vector_type(2)));
typedef unsigned long long u64;

static __device__ __forceinline__ u32 umin32(u32 a, u32 b) { return b < a ? b : a; }

template <int CTRL>
static __device__ __forceinline__ u32 dpp_min(u32 m) {
  return umin32(m, (u32)__builtin_amdgcn_mov_dpp((int)m, CTRL, 0xF, 0xF, true));
}
static __device__ __forceinline__ u32 x16_min(u32 m) {
#if __has_builtin(__builtin_amdgcn_permlane16_swap)
  auto r = __builtin_amdgcn_permlane16_swap((int)m, (int)m, false, false);
  return umin32(m, umin32((u32)r[0], (u32)r[1]));
#else
  return umin32(m, (u32)__builtin_amdgcn_ds_swizzle((int)m, 0x401F));
#endif
}
static __device__ __forceinline__ u32 x32_min(u32 m) {
#if __has_builtin(__builtin_amdgcn_permlane32_swap)
  auto r = __builtin_amdgcn_permlane32_swap((int)m, (int)m, false, false);
  return umin32(m, umin32((u32)r[0], (u32)r[1]));
#else
  return umin32(m, (u32)__shfl_xor((int)m, 32, 64));
#endif
}
// 0 or 0xFFFFFFFF from bit c of mask (v_bfe_i32, width 1).
static __device__ __forceinline__ u32 sext_bit(u32 mask, int c) {
#if __has_builtin(__builtin_amdgcn_sbfe)
  return (u32)__builtin_amdgcn_sbfe((int)mask, c, 1);
#else
  return (u32)(((int)(mask << (31 - c))) >> 31);
#endif
}

#define FOR16(M) M(0) M(1) M(2) M(3) M(4) M(5) M(6) M(7) \
                 M(8) M(9) M(10) M(11) M(12) M(13) M(14) M(15)

// Load target pair h (columns 2h, 2h+1 of this lane's 32) into NAMED regs.
#define LOADP(h) \
  v2f TX##h, TY##h, TZ##h, TQ##h; \
  { float x0 = tb[6*h+0], y0 = tb[6*h+1], z0 = tb[6*h+2]; \
    float x1 = tb[6*h+3], y1 = tb[6*h+4], z1 = tb[6*h+5]; \
    TX##h = (v2f){x0, x1}; TY##h = (v2f){y0, y1}; TZ##h = (v2f){z0, z1}; \
    TQ##h = (v2f){x0*x0 + y0*y0 + z0*z0, x1*x1 + y1*y1 + z1*z1}; }

#define DECLRU(h) v2u RU##h;

// Raw distance keys for the CURRENT (Xv,Yv,Zv,Qv) row. Exact ref arithmetic:
// d2 = Q + fma(-2, fma(tx,X, fma(ty,Y, tz*Z)), tq). Positive-float bits
// order as u32 (d2 ~ 1e-3..1e2 for this data; clamp applied only at sqrt).
#define DIST(h) { \
  v2f dot = __builtin_elementwise_fma(TX##h, Xv, \
              __builtin_elementwise_fma(TY##h, Yv, TZ##h * Zv)); \
  v2f dd  = __builtin_elementwise_fma(m2v, dot, TQ##h); \
  v2f d2  = Qv + dd; \
  RU##h = (v2u){(u32)__float_as_int(d2.x), (u32)__float_as_int(d2.y)}; }

// Masked (val,idx) tournament node; chain c covers CONTIGUOUS pairs so the
// left-preferring merges keep exact smallest-index tie-breaking.
#define TOUR(h, c) { \
  u32 u0 = RU##h.x | sext_bit(usedmask, 2*h); \
  u32 u1 = RU##h.y | sext_bit(usedmask, 2*h + 1); \
  u32 pu = umin32(u0, u1); \
  u32 pk = (u1 < u0) ? (u32)(2*h + 1) : (u32)(2*h); \
  if (pu < bc##c) { bc##c = pu; kc##c = pk; } }

__global__ __launch_bounds__(64, 1) void emd_greedy_kernel(
    const float* __restrict__ pred, const float* __restrict__ target,
    float* __restrict__ batch_sums) {
  const int b = blockIdx.x, lane = threadIdx.x;
  const float* p = pred + (size_t)b * NPTS * 3;
  const float* t = target + (size_t)b * NPTS * 3;

  __shared__ float4 pp[NPTS + 2];
  for (int i = lane; i < NPTS; i += 64) {
    float x = p[3 * i], y = p[3 * i + 1], z = p[3 * i + 2];
    pp[i] = make_float4(x, y, z, x * x + y * y + z * z);
  }
  if (lane < 2) pp[NPTS + lane] = make_float4(0.f, 0.f, 0.f, 0.f);

  const float* tb = t + (size_t)lane * 32 * 3;  // this lane's 32 columns
  FOR16(LOADP)
  FOR16(DECLRU)

  u32 usedmask = 0;
  float sum = 0.f;
  __syncthreads();

  const v2f m2v = {-2.f, -2.f};
  v2f Xv, Yv, Zv, Qv;

  // Prologue: raw keys for row 0.
  {
    float4 A = pp[0];
    Xv = (v2f){A.x, A.x}; Yv = (v2f){A.y, A.y};
    Zv = (v2f){A.z, A.z}; Qv = (v2f){A.w, A.w};
    FOR16(DIST)
  }

  for (int i = 0; i < NPTS; ++i) {
    float4 An = pp[i + 1];  // ds_read_b128, hidden under the tournament

    // Masked tournament over row i's raw keys (4 contiguous chains).
    u32 bc0 = ~0u, bc1 = ~0u, bc2 = ~0u, bc3 = ~0u;
    u32 kc0 = 0, kc1 = 0, kc2 = 0, kc3 = 0;
    TOUR(0, 0)  TOUR(1, 0)  TOUR(2, 0)  TOUR(3, 0)
    TOUR(4, 1)  TOUR(5, 1)  TOUR(6, 1)  TOUR(7, 1)
    TOUR(8, 2)  TOUR(9, 2)  TOUR(10, 2) TOUR(11, 2)
    TOUR(12, 3) TOUR(13, 3) TOUR(14, 3) TOUR(15, 3)
    // Left-preferring merges (left chains hold strictly smaller indices).
    bool s01 = bc1 < bc0; u32 v01 = s01 ? bc1 : bc0; u32 i01 = s01 ? kc1 : kc0;
    bool s23 = bc3 < bc2; u32 v23 = s23 ? bc3 : bc2; u32 i23 = s23 ? kc3 : kc2;
    bool sf  = v23 < v01; u32 bu  = sf ? v23 : v01; u32 bk  = sf ? i23 : i01;

    // Row i+1 raw keys — independent of row i's reduce; the scheduler
    // interleaves these 80 packed FMAs into the reduce-chain stalls.
    Xv = (v2f){An.x, An.x}; Yv = (v2f){An.y, An.y};
    Zv = (v2f){An.z, An.z}; Qv = (v2f){An.w, An.w};
    FOR16(DIST)

    // All-VALU wave-wide u32 min.
    u32 m = bu;
    m = dpp_min<0xB1>(m);   // xor 1
    m = dpp_min<0x4E>(m);   // xor 2
    m = dpp_min<0x141>(m);  // row_half_mirror (covers xor 4 after 1,2)
    m = dpp_min<0x140>(m);  // row_mirror (covers xor 8)
    m = x16_min(m);         // lane ^ 16
    m = x32_min(m);         // lane ^ 32

    // Winner = smallest lane with bu == m (= smallest global j on ties,
    // since lanes own contiguous column blocks). It flips its own bit.
    u64 mk = __ballot(bu == m);
    int first = __ffsll(mk) - 1;
    usedmask |= (lane == first) ? (1u << bk) : 0u;
    sum += sqrtf(fmaxf(__uint_as_float(m), 1e-12f));
  }
  if (lane == 0) batch_sums[b] = sum;
}

// mean over batches of (per-batch sum / N)
__global__ void emd_finalize_kernel(const float* __restrict__ batch_sums,
                                    float* __restrict__ out, int B) {
  float acc = 0.f;
  for (int b = 0; b < B; ++b) acc += batch_sums[b] / (float)NPTS;
  out[0] = acc / (float)B;
}

extern "C" void kernel_launch(void* const* d_in, const int* in_sizes, int n_in,
                              void* d_out, int out_size, void* d_ws, size_t ws_size,
                              hipStream_t stream) {
  const float* pred   = (const float*)d_in[0];
  const float* target = (const float*)d_in[1];
  float* ws  = (float*)d_ws;
  float* out = (float*)d_out;
  const int B = in_sizes[0] / (NPTS * 3);

  emd_greedy_kernel<<<B, 64, 0, stream>>>(pred, target, ws);
  emd_finalize_kernel<<<1, 1, 0, stream>>>(ws, out, B);
}

// Round 5
// 1159.761 us; speedup vs baseline: 1.2161x; 1.0003x over previous
//
#include <hip/hip_runtime.h>

#define NPTS 2048

typedef float v2f __attribute__((ext_vector_type(2)));
typedef unsigned int u32;
typedef u32 v2u __attribute__((ext_vector_type(2)));
typedef unsigned long long u64;

static __device__ __forceinline__ u32 umin32(u32 a, u32 b) { return b < a ? b : a; }

template <int CTRL>
static __device__ __forceinline__ u32 dpp_min(u32 m) {
  return umin32(m, (u32)__builtin_amdgcn_mov_dpp((int)m, CTRL, 0xF, 0xF, true));
}
static __device__ __forceinline__ u32 x16_min(u32 m) {
#if __has_builtin(__builtin_amdgcn_permlane16_swap)
  auto r = __builtin_amdgcn_permlane16_swap((int)m, (int)m, false, false);
  return umin32(m, umin32((u32)r[0], (u32)r[1]));
#else
  return umin32(m, (u32)__builtin_amdgcn_ds_swizzle((int)m, 0x401F));
#endif
}
static __device__ __forceinline__ u32 x32_min(u32 m) {
#if __has_builtin(__builtin_amdgcn_permlane32_swap)
  auto r = __builtin_amdgcn_permlane32_swap((int)m, (int)m, false, false);
  return umin32(m, umin32((u32)r[0], (u32)r[1]));
#else
  return umin32(m, (u32)__shfl_xor((int)m, 32, 64));
#endif
}
// 0 or 0xFFFFFFFF from bit c of mask (v_bfe_i32, width 1).
static __device__ __forceinline__ u32 sext_bit(u32 mask, int c) {
#if __has_builtin(__builtin_amdgcn_sbfe)
  return (u32)__builtin_amdgcn_sbfe((int)mask, c, 1);
#else
  return (u32)(((int)(mask << (31 - c))) >> 31);
#endif
}

#define FOR16(M) M(0) M(1) M(2) M(3) M(4) M(5) M(6) M(7) \
                 M(8) M(9) M(10) M(11) M(12) M(13) M(14) M(15)

// Load target pair h (columns 2h, 2h+1 of this lane's 32) into NAMED regs.
#define LOADP(h) \
  v2f TX##h, TY##h, TZ##h, TQ##h; \
  { float x0 = tb[6*h+0], y0 = tb[6*h+1], z0 = tb[6*h+2]; \
    float x1 = tb[6*h+3], y1 = tb[6*h+4], z1 = tb[6*h+5]; \
    TX##h = (v2f){x0, x1}; TY##h = (v2f){y0, y1}; TZ##h = (v2f){z0, z1}; \
    TQ##h = (v2f){x0*x0 + y0*y0 + z0*z0, x1*x1 + y1*y1 + z1*z1}; }

// Force true register residency: the asm "defines" the value, so the
// original global loads cannot be rematerialized inside the row loop.
#define PIN(h) \
  asm volatile("" : "+v"(TX##h), "+v"(TY##h), "+v"(TZ##h), "+v"(TQ##h));

#define DECLRU(h) v2u RU##h;

// Raw distance keys for the CURRENT (Xv,Yv,Zv,Qv) row. Exact ref arithmetic:
// d2 = Q + fma(-2, fma(tx,X, fma(ty,Y, tz*Z)), tq). Positive-float bits
// order as u32 (d2 ~ 1e-3..1e2 for this data; clamp applied only at sqrt).
#define DIST(h) { \
  v2f dot = __builtin_elementwise_fma(TX##h, Xv, \
              __builtin_elementwise_fma(TY##h, Yv, TZ##h * Zv)); \
  v2f dd  = __builtin_elementwise_fma(m2v, dot, TQ##h); \
  v2f d2  = Qv + dd; \
  RU##h = (v2u){(u32)__float_as_int(d2.x), (u32)__float_as_int(d2.y)}; }

// Masked (val,idx) tournament node; chain c covers CONTIGUOUS pairs so the
// left-preferring merges keep exact smallest-index tie-breaking.
#define TOUR(h, c) { \
  u32 u0 = RU##h.x | sext_bit(usedmask, 2*h); \
  u32 u1 = RU##h.y | sext_bit(usedmask, 2*h + 1); \
  u32 pu = umin32(u0, u1); \
  u32 pk = (u1 < u0) ? (u32)(2*h + 1) : (u32)(2*h); \
  if (pu < bc##c) { bc##c = pu; kc##c = pk; } }

__global__ __launch_bounds__(64, 1) void emd_greedy_kernel(
    const float* __restrict__ pred, const float* __restrict__ target,
    float* __restrict__ batch_sums) {
  const int b = blockIdx.x, lane = threadIdx.x;
  const float* p = pred + (size_t)b * NPTS * 3;
  const float* t = target + (size_t)b * NPTS * 3;

  __shared__ float4 pp[NPTS + 2];
  for (int i = lane; i < NPTS; i += 64) {
    float x = p[3 * i], y = p[3 * i + 1], z = p[3 * i + 2];
    pp[i] = make_float4(x, y, z, x * x + y * y + z * z);
  }
  if (lane < 2) pp[NPTS + lane] = make_float4(0.f, 0.f, 0.f, 0.f);

  const float* tb = t + (size_t)lane * 32 * 3;  // this lane's 32 columns
  FOR16(LOADP)
  FOR16(PIN)
  FOR16(DECLRU)

  u32 usedmask = 0;
  float sum = 0.f;
  __syncthreads();

  const v2f m2v = {-2.f, -2.f};
  v2f Xv, Yv, Zv, Qv;

  // Prologue: raw keys for row 0.
  {
    float4 A = pp[0];
    Xv = (v2f){A.x, A.x}; Yv = (v2f){A.y, A.y};
    Zv = (v2f){A.z, A.z}; Qv = (v2f){A.w, A.w};
    FOR16(DIST)
  }

  for (int i = 0; i < NPTS; ++i) {
    float4 An = pp[i + 1];  // ds_read_b128, hidden under the tournament

    // Masked tournament over row i's raw keys (4 contiguous chains).
    u32 bc0 = ~0u, bc1 = ~0u, bc2 = ~0u, bc3 = ~0u;
    u32 kc0 = 0, kc1 = 0, kc2 = 0, kc3 = 0;
    TOUR(0, 0)  TOUR(1, 0)  TOUR(2, 0)  TOUR(3, 0)
    TOUR(4, 1)  TOUR(5, 1)  TOUR(6, 1)  TOUR(7, 1)
    TOUR(8, 2)  TOUR(9, 2)  TOUR(10, 2) TOUR(11, 2)
    TOUR(12, 3) TOUR(13, 3) TOUR(14, 3) TOUR(15, 3)
    // Left-preferring merges (left chains hold strictly smaller indices).
    bool s01 = bc1 < bc0; u32 v01 = s01 ? bc1 : bc0; u32 i01 = s01 ? kc1 : kc0;
    bool s23 = bc3 < bc2; u32 v23 = s23 ? bc3 : bc2; u32 i23 = s23 ? kc3 : kc2;
    bool sf  = v23 < v01; u32 bu  = sf ? v23 : v01; u32 bk  = sf ? i23 : i01;

    // Row i+1 raw keys — independent of row i's reduce; the scheduler
    // interleaves these packed FMAs into the reduce-chain stalls.
    Xv = (v2f){An.x, An.x}; Yv = (v2f){An.y, An.y};
    Zv = (v2f){An.z, An.z}; Qv = (v2f){An.w, An.w};
    FOR16(DIST)

    // All-VALU wave-wide u32 min.
    u32 m = bu;
    m = dpp_min<0xB1>(m);   // xor 1
    m = dpp_min<0x4E>(m);   // xor 2
    m = dpp_min<0x141>(m);  // row_half_mirror (covers xor 4 after 1,2)
    m = dpp_min<0x140>(m);  // row_mirror (covers xor 8)
    m = x16_min(m);         // lane ^ 16
    m = x32_min(m);         // lane ^ 32

    // Winner = smallest lane with bu == m (= smallest global j on ties,
    // since lanes own contiguous column blocks). It flips its own bit.
    u64 mk = __ballot(bu == m);
    int first = __ffsll(mk) - 1;
    usedmask |= (lane == first) ? (1u << bk) : 0u;
    sum += sqrtf(fmaxf(__uint_as_float(m), 1e-12f));
  }
  if (lane == 0) batch_sums[b] = sum;
}

// mean over batches of (per-batch sum / N)
__global__ void emd_finalize_kernel(const float* __restrict__ batch_sums,
                                    float* __restrict__ out, int B) {
  float acc = 0.f;
  for (int b = 0; b < B; ++b) acc += batch_sums[b] / (float)NPTS;
  out[0] = acc / (float)B;
}

extern "C" void kernel_launch(void* const* d_in, const int* in_sizes, int n_in,
                              void* d_out, int out_size, void* d_ws, size_t ws_size,
                              hipStream_t stream) {
  const float* pred   = (const float*)d_in[0];
  const float* target = (const float*)d_in[1];
  float* ws  = (float*)d_ws;
  float* out = (float*)d_out;
  const int B = in_sizes[0] / (NPTS * 3);

  emd_greedy_kernel<<<B, 64, 0, stream>>>(pred, target, ws);
  emd_finalize_kernel<<<1, 1, 0, stream>>>(ws, out, B);
}

// Round 6
// 973.264 us; speedup vs baseline: 1.4491x; 1.1916x over previous
//
#include <hip/hip_runtime.h>

#define NPTS 2048
#define TOPK 32

typedef float v2f __attribute__((ext_vector_type(2)));
typedef unsigned int u32;
typedef u32 v2u __attribute__((ext_vector_type(2)));
typedef unsigned long long u64;

// ---------- common helpers ----------
static __device__ __forceinline__ u32 umin32(u32 a, u32 b) { return b < a ? b : a; }
static __device__ __forceinline__ u64 umin64(u64 a, u64 b) { return b < a ? b : a; }

template <int CTRL>
static __device__ __forceinline__ u32 dpp_min(u32 m) {
  return umin32(m, (u32)__builtin_amdgcn_mov_dpp((int)m, CTRL, 0xF, 0xF, true));
}
static __device__ __forceinline__ u32 x16_min(u32 m) {
#if __has_builtin(__builtin_amdgcn_permlane16_swap)
  auto r = __builtin_amdgcn_permlane16_swap((int)m, (int)m, false, false);
  return umin32(m, umin32((u32)r[0], (u32)r[1]));
#else
  return umin32(m, (u32)__builtin_amdgcn_ds_swizzle((int)m, 0x401F));
#endif
}
static __device__ __forceinline__ u32 x32_min(u32 m) {
#if __has_builtin(__builtin_amdgcn_permlane32_swap)
  auto r = __builtin_amdgcn_permlane32_swap((int)m, (int)m, false, false);
  return umin32(m, umin32((u32)r[0], (u32)r[1]));
#else
  return umin32(m, (u32)__shfl_xor((int)m, 32, 64));
#endif
}
static __device__ __forceinline__ u32 sext_bit(u32 mask, int c) {
#if __has_builtin(__builtin_amdgcn_sbfe)
  return (u32)__builtin_amdgcn_sbfe((int)mask, c, 1);
#else
  return (u32)(((int)(mask << (31 - c))) >> 31);
#endif
}

// u64 wave-min (verified in round 3, absmax 0)
template <int CTRL>
static __device__ __forceinline__ u64 dpp_min64(u64 k) {
  unsigned lo = (unsigned)k, hi = (unsigned)(k >> 32);
  unsigned olo = (unsigned)__builtin_amdgcn_mov_dpp((int)lo, CTRL, 0xF, 0xF, true);
  unsigned ohi = (unsigned)__builtin_amdgcn_mov_dpp((int)hi, CTRL, 0xF, 0xF, true);
  return umin64(k, ((u64)ohi << 32) | olo);
}
static __device__ __forceinline__ u64 x16_min64(u64 k) {
  unsigned lo = (unsigned)k, hi = (unsigned)(k >> 32);
#if __has_builtin(__builtin_amdgcn_permlane16_swap)
  auto rlo = __builtin_amdgcn_permlane16_swap(lo, lo, false, false);
  auto rhi = __builtin_amdgcn_permlane16_swap(hi, hi, false, false);
  u64 a = ((u64)rhi[0] << 32) | rlo[0];
  u64 b = ((u64)rhi[1] << 32) | rlo[1];
  return umin64(k, umin64(a, b));
#else
  unsigned olo = (unsigned)__builtin_amdgcn_ds_swizzle((int)lo, 0x401F);
  unsigned ohi = (unsigned)__builtin_amdgcn_ds_swizzle((int)hi, 0x401F);
  return umin64(k, ((u64)ohi << 32) | olo);
#endif
}
static __device__ __forceinline__ u64 x32_min64(u64 k) {
  unsigned lo = (unsigned)k, hi = (unsigned)(k >> 32);
#if __has_builtin(__builtin_amdgcn_permlane32_swap)
  auto rlo = __builtin_amdgcn_permlane32_swap(lo, lo, false, false);
  auto rhi = __builtin_amdgcn_permlane32_swap(hi, hi, false, false);
  u64 a = ((u64)rhi[0] << 32) | rlo[0];
  u64 b = ((u64)rhi[1] << 32) | rlo[1];
  return umin64(k, umin64(a, b));
#else
  unsigned olo = (unsigned)__shfl_xor((int)lo, 32, 64);
  unsigned ohi = (unsigned)__shfl_xor((int)hi, 32, 64);
  return umin64(k, ((u64)ohi << 32) | olo);
#endif
}
static __device__ __forceinline__ u64 wave_min_u64(u64 k) {
  k = dpp_min64<0xB1>(k);
  k = dpp_min64<0x4E>(k);
  k = dpp_min64<0x141>(k);
  k = dpp_min64<0x140>(k);
  k = x16_min64(k);
  k = x32_min64(k);
  return k;  // wave-uniform
}

// LDS layout for per-lane strided float4 reads without bank conflicts:
// column c -> tt[((c&31)<<6) | (c>>5)]; lane reads tt[(k<<6)|lane].
#define TT_IDX(c) ((((c) & 31) << 6) | ((c) >> 5))

#define FOR32(M) M(0) M(1) M(2) M(3) M(4) M(5) M(6) M(7) \
                 M(8) M(9) M(10) M(11) M(12) M(13) M(14) M(15) \
                 M(16) M(17) M(18) M(19) M(20) M(21) M(22) M(23) \
                 M(24) M(25) M(26) M(27) M(28) M(29) M(30) M(31)

// ---------- phase 1: exact per-row top-32 (fully parallel) ----------
// Key = (clamped_d2_bits << 32) | column  => u64 order == (dist, idx) lex
// order == reference argmin-with-ties order. 32 extract-min iterations
// emit the list in ascending order.
#define MKK(k) u64 K##k; { \
  float4 c = tt[((k) << 6) | lane]; \
  float dot = fmaf(c.x, X, fmaf(c.y, Y, c.z * Z)); \
  float d2  = Q + fmaf(-2.f, dot, c.w); \
  d2 = fmaxf(d2, 1e-12f); \
  K##k = ((u64)(u32)__float_as_int(d2) << 32) | (u32)((lane << 5) + (k)); }

#define PZ(k) case (k): K##k = ~0ULL; break;

__global__ __launch_bounds__(64) void emd_topk_kernel(
    const float* __restrict__ pred, const float* __restrict__ target,
    u64* __restrict__ lists) {
  const int bid = blockIdx.x;
  const int b = bid >> 11, i = bid & (NPTS - 1);
  const int lane = threadIdx.x;
  const float* p = pred + (size_t)b * NPTS * 3;
  const float* t = target + (size_t)b * NPTS * 3;

  __shared__ float4 tt[NPTS];
  for (int j = lane; j < NPTS; j += 64) {
    float x = t[3 * j], y = t[3 * j + 1], z = t[3 * j + 2];
    tt[TT_IDX(j)] = make_float4(x, y, z, fmaf(x, x, fmaf(y, y, z * z)));
  }
  __syncthreads();

  const float X = p[3 * i], Y = p[3 * i + 1], Z = p[3 * i + 2];
  const float Q = fmaf(X, X, fmaf(Y, Y, Z * Z));
  FOR32(MKK)

  u64* out = lists + (size_t)bid * TOPK;
  for (int e = 0; e < TOPK; ++e) {
    u64 m;
    {
      u64 a0 = umin64(K0, K1),   a1 = umin64(K2, K3),   a2 = umin64(K4, K5),   a3 = umin64(K6, K7);
      u64 a4 = umin64(K8, K9),   a5 = umin64(K10, K11), a6 = umin64(K12, K13), a7 = umin64(K14, K15);
      u64 a8 = umin64(K16, K17), a9 = umin64(K18, K19), a10 = umin64(K20, K21), a11 = umin64(K22, K23);
      u64 a12 = umin64(K24, K25), a13 = umin64(K26, K27), a14 = umin64(K28, K29), a15 = umin64(K30, K31);
      u64 b0 = umin64(a0, a1), b1 = umin64(a2, a3), b2 = umin64(a4, a5), b3 = umin64(a6, a7);
      u64 b4 = umin64(a8, a9), b5 = umin64(a10, a11), b6 = umin64(a12, a13), b7 = umin64(a14, a15);
      u64 c0 = umin64(b0, b1), c1 = umin64(b2, b3), c2 = umin64(b4, b5), c3 = umin64(b6, b7);
      m = umin64(umin64(c0, c1), umin64(c2, c3));
    }
    m = wave_min_u64(m);
    if (lane == 0) out[e] = m;
    const u32 idx = (u32)m & (u32)(NPTS - 1);
    if (lane == (int)(idx >> 5)) {
      switch (idx & 31u) { FOR32(PZ) }
    }
  }
}

// ---------- phase 2: sequential greedy via candidate probes ----------
// Fast path per row: lane r holds candidate r of the sorted top-32; its
// used-bit is fetched from the owning lane's register usedmask via
// ds_bpermute; first free rank (ballot+ffs) is the exact argmin. Fallback
// (all 32 used): full masked search from LDS targets with u64 keys.
#define PROC(C, ROW) { \
  u32 cc = (u32)(C) & (u32)(NPTS - 1); \
  u32 ow = (u32)__builtin_amdgcn_ds_bpermute((int)((cc >> 5) << 2), (int)usedmask); \
  bool fr = (((ow >> (cc & 31u)) & 1u) == 0u) && (lane < TOPK); \
  u64 bl = __ballot(fr); \
  if (bl != 0) { \
    int R = __ffsll(bl) - 1; \
    u32 mlo = (u32)__builtin_amdgcn_readlane((int)(u32)(C), R); \
    u32 mhi = (u32)__builtin_amdgcn_readlane((int)(u32)((C) >> 32), R); \
    u32 cs = mlo & (u32)(NPTS - 1); \
    usedmask |= (lane == (int)(cs >> 5)) ? (1u << (cs & 31u)) : 0u; \
    sum += sqrtf(__uint_as_float(mhi)); \
  } else { \
    float X = p[3 * (ROW)], Y = p[3 * (ROW) + 1], Z = p[3 * (ROW) + 2]; \
    float Q = fmaf(X, X, fmaf(Y, Y, Z * Z)); \
    u64 best = ~0ULL; \
    for (int k = 0; k < 32; ++k) { \
      float4 c4 = tt[(k << 6) | lane]; \
      float dot = fmaf(c4.x, X, fmaf(c4.y, Y, c4.z * Z)); \
      float d2 = Q + fmaf(-2.f, dot, c4.w); \
      d2 = fmaxf(d2, 1e-12f); \
      u64 key = ((u64)(u32)__float_as_int(d2) << 32) | (u32)((lane << 5) + k); \
      if ((usedmask >> k) & 1u) key = ~0ULL; \
      best = umin64(best, key); \
    } \
    u64 m = wave_min_u64(best); \
    u32 cs = (u32)m & (u32)(NPTS - 1); \
    usedmask |= (lane == (int)(cs >> 5)) ? (1u << (cs & 31u)) : 0u; \
    sum += sqrtf(__uint_as_float((u32)(m >> 32))); \
  } }

__global__ __launch_bounds__(64, 1) void emd_seq_kernel(
    const float* __restrict__ pred, const float* __restrict__ target,
    const u64* __restrict__ lists, float* __restrict__ batch_sums) {
  const int b = blockIdx.x, lane = threadIdx.x;
  const float* p = pred + (size_t)b * NPTS * 3;
  const float* t = target + (size_t)b * NPTS * 3;

  __shared__ float4 tt[NPTS];  // for fallback rows
  for (int j = lane; j < NPTS; j += 64) {
    float x = t[3 * j], y = t[3 * j + 1], z = t[3 * j + 2];
    tt[TT_IDX(j)] = make_float4(x, y, z, fmaf(x, x, fmaf(y, y, z * z)));
  }
  __syncthreads();

  const u64* L = lists + (size_t)b * NPTS * TOPK;
  const int li = lane & (TOPK - 1);  // all 64 lanes load valid entries
  u32 usedmask = 0;
  float sum = 0.f;

  // 8-deep register prefetch of candidate lists (covers L3 latency).
  u64 C0 = L[(size_t)0 * TOPK + li], C1 = L[(size_t)1 * TOPK + li];
  u64 C2 = L[(size_t)2 * TOPK + li], C3 = L[(size_t)3 * TOPK + li];
  u64 C4 = L[(size_t)4 * TOPK + li], C5 = L[(size_t)5 * TOPK + li];
  u64 C6 = L[(size_t)6 * TOPK + li], C7 = L[(size_t)7 * TOPK + li];

#define NEXTROW(d) ((size_t)((i + 8 + (d) < NPTS) ? (i + 8 + (d)) : (NPTS - 1)))
  for (int i = 0; i < NPTS; i += 8) {
    PROC(C0, i + 0) C0 = L[NEXTROW(0) * TOPK + li];
    PROC(C1, i + 1) C1 = L[NEXTROW(1) * TOPK + li];
    PROC(C2, i + 2) C2 = L[NEXTROW(2) * TOPK + li];
    PROC(C3, i + 3) C3 = L[NEXTROW(3) * TOPK + li];
    PROC(C4, i + 4) C4 = L[NEXTROW(4) * TOPK + li];
    PROC(C5, i + 5) C5 = L[NEXTROW(5) * TOPK + li];
    PROC(C6, i + 6) C6 = L[NEXTROW(6) * TOPK + li];
    PROC(C7, i + 7) C7 = L[NEXTROW(7) * TOPK + li];
  }
#undef NEXTROW
  if (lane == 0) batch_sums[b] = sum;
}

// ---------- legacy single-kernel path (round-5, proven) ----------
#define FOR16(M) M(0) M(1) M(2) M(3) M(4) M(5) M(6) M(7) \
                 M(8) M(9) M(10) M(11) M(12) M(13) M(14) M(15)
#define LOADP(h) \
  v2f TX##h, TY##h, TZ##h, TQ##h; \
  { float x0 = tb[6*h+0], y0 = tb[6*h+1], z0 = tb[6*h+2]; \
    float x1 = tb[6*h+3], y1 = tb[6*h+4], z1 = tb[6*h+5]; \
    TX##h = (v2f){x0, x1}; TY##h = (v2f){y0, y1}; TZ##h = (v2f){z0, z1}; \
    TQ##h = (v2f){x0*x0 + y0*y0 + z0*z0, x1*x1 + y1*y1 + z1*z1}; }
#define DECLRU(h) v2u RU##h;
#define DIST(h) { \
  v2f dot = __builtin_elementwise_fma(TX##h, Xv, \
              __builtin_elementwise_fma(TY##h, Yv, TZ##h * Zv)); \
  v2f dd  = __builtin_elementwise_fma(m2v, dot, TQ##h); \
  v2f d2  = Qv + dd; \
  RU##h = (v2u){(u32)__float_as_int(d2.x), (u32)__float_as_int(d2.y)}; }
#define TOUR(h, c) { \
  u32 u0 = RU##h.x | sext_bit(usedmask, 2*h); \
  u32 u1 = RU##h.y | sext_bit(usedmask, 2*h + 1); \
  u32 pu = umin32(u0, u1); \
  u32 pk = (u1 < u0) ? (u32)(2*h + 1) : (u32)(2*h); \
  if (pu < bc##c) { bc##c = pu; kc##c = pk; } }

__global__ __launch_bounds__(64, 1) void emd_greedy_kernel(
    const float* __restrict__ pred, const float* __restrict__ target,
    float* __restrict__ batch_sums) {
  const int b = blockIdx.x, lane = threadIdx.x;
  const float* p = pred + (size_t)b * NPTS * 3;
  const float* t = target + (size_t)b * NPTS * 3;
  __shared__ float4 pp[NPTS + 2];
  for (int i = lane; i < NPTS; i += 64) {
    float x = p[3 * i], y = p[3 * i + 1], z = p[3 * i + 2];
    pp[i] = make_float4(x, y, z, x * x + y * y + z * z);
  }
  if (lane < 2) pp[NPTS + lane] = make_float4(0.f, 0.f, 0.f, 0.f);
  const float* tb = t + (size_t)lane * 32 * 3;
  FOR16(LOADP)
  FOR16(DECLRU)
  u32 usedmask = 0;
  float sum = 0.f;
  __syncthreads();
  const v2f m2v = {-2.f, -2.f};
  v2f Xv, Yv, Zv, Qv;
  {
    float4 A = pp[0];
    Xv = (v2f){A.x, A.x}; Yv = (v2f){A.y, A.y};
    Zv = (v2f){A.z, A.z}; Qv = (v2f){A.w, A.w};
    FOR16(DIST)
  }
  for (int i = 0; i < NPTS; ++i) {
    float4 An = pp[i + 1];
    u32 bc0 = ~0u, bc1 = ~0u, bc2 = ~0u, bc3 = ~0u;
    u32 kc0 = 0, kc1 = 0, kc2 = 0, kc3 = 0;
    TOUR(0, 0)  TOUR(1, 0)  TOUR(2, 0)  TOUR(3, 0)
    TOUR(4, 1)  TOUR(5, 1)  TOUR(6, 1)  TOUR(7, 1)
    TOUR(8, 2)  TOUR(9, 2)  TOUR(10, 2) TOUR(11, 2)
    TOUR(12, 3) TOUR(13, 3) TOUR(14, 3) TOUR(15, 3)
    bool s01 = bc1 < bc0; u32 v01 = s01 ? bc1 : bc0; u32 i01 = s01 ? kc1 : kc0;
    bool s23 = bc3 < bc2; u32 v23 = s23 ? bc3 : bc2; u32 i23 = s23 ? kc3 : kc2;
    bool sf  = v23 < v01; u32 bu  = sf ? v23 : v01; u32 bk  = sf ? i23 : i01;
    Xv = (v2f){An.x, An.x}; Yv = (v2f){An.y, An.y};
    Zv = (v2f){An.z, An.z}; Qv = (v2f){An.w, An.w};
    FOR16(DIST)
    u32 m = bu;
    m = dpp_min<0xB1>(m); m = dpp_min<0x4E>(m);
    m = dpp_min<0x141>(m); m = dpp_min<0x140>(m);
    m = x16_min(m); m = x32_min(m);
    u64 mk = __ballot(bu == m);
    int first = __ffsll(mk) - 1;
    usedmask |= (lane == first) ? (1u << bk) : 0u;
    sum += sqrtf(fmaxf(__uint_as_float(m), 1e-12f));
  }
  if (lane == 0) batch_sums[b] = sum;
}

// ---------- finalize ----------
__global__ void emd_finalize_kernel(const float* __restrict__ batch_sums,
                                    float* __restrict__ out, int B) {
  float acc = 0.f;
  for (int b = 0; b < B; ++b) acc += batch_sums[b] / (float)NPTS;
  out[0] = acc / (float)B;
}

extern "C" void kernel_launch(void* const* d_in, const int* in_sizes, int n_in,
                              void* d_out, int out_size, void* d_ws, size_t ws_size,
                              hipStream_t stream) {
  const float* pred   = (const float*)d_in[0];
  const float* target = (const float*)d_in[1];
  float* out = (float*)d_out;
  const int B = in_sizes[0] / (NPTS * 3);

  const size_t need = 256 + (size_t)B * NPTS * TOPK * sizeof(u64);
  if (ws_size >= need) {
    float* bs = (float*)d_ws;
    u64* lists = (u64*)((char*)d_ws + 256);
    emd_topk_kernel<<<B * NPTS, 64, 0, stream>>>(pred, target, lists);
    emd_seq_kernel<<<B, 64, 0, stream>>>(pred, target, lists, bs);
    emd_finalize_kernel<<<1, 1, 0, stream>>>(bs, out, B);
  } else {
    float* bs = (float*)d_ws;
    emd_greedy_kernel<<<B, 64, 0, stream>>>(pred, target, bs);
    emd_finalize_kernel<<<1, 1, 0, stream>>>(bs, out, B);
  }
}

// Round 7
// 742.811 us; speedup vs baseline: 1.8986x; 1.3102x over previous
//
#include <hip/hip_runtime.h>

#define NPTS 2048
#define TOPK 32
#define RPB  8   // rows per block in phase 1

typedef float v2f __attribute__((ext_vector_type(2)));
typedef unsigned int u32;
typedef u32 v2u __attribute__((ext_vector_type(2)));
typedef unsigned long long u64;

// ---------- helpers ----------
static __device__ __forceinline__ u32 umin32(u32 a, u32 b) { return b < a ? b : a; }
static __device__ __forceinline__ u64 umin64(u64 a, u64 b) { return b < a ? b : a; }

template <int CTRL>
static __device__ __forceinline__ u32 dpp_min(u32 m) {
  return umin32(m, (u32)__builtin_amdgcn_mov_dpp((int)m, CTRL, 0xF, 0xF, true));
}
static __device__ __forceinline__ u32 x16_min(u32 m) {
#if __has_builtin(__builtin_amdgcn_permlane16_swap)
  auto r = __builtin_amdgcn_permlane16_swap((int)m, (int)m, false, false);
  return umin32(m, umin32((u32)r[0], (u32)r[1]));
#else
  return umin32(m, (u32)__builtin_amdgcn_ds_swizzle((int)m, 0x401F));
#endif
}
static __device__ __forceinline__ u32 x32_min(u32 m) {
#if __has_builtin(__builtin_amdgcn_permlane32_swap)
  auto r = __builtin_amdgcn_permlane32_swap((int)m, (int)m, false, false);
  return umin32(m, umin32((u32)r[0], (u32)r[1]));
#else
  return umin32(m, (u32)__shfl_xor((int)m, 32, 64));
#endif
}
static __device__ __forceinline__ u32 sext_bit(u32 mask, int c) {
#if __has_builtin(__builtin_amdgcn_sbfe)
  return (u32)__builtin_amdgcn_sbfe((int)mask, c, 1);
#else
  return (u32)(((int)(mask << (31 - c))) >> 31);
#endif
}

template <int CTRL>
static __device__ __forceinline__ u64 dpp_min64(u64 k) {
  unsigned lo = (unsigned)k, hi = (unsigned)(k >> 32);
  unsigned olo = (unsigned)__builtin_amdgcn_mov_dpp((int)lo, CTRL, 0xF, 0xF, true);
  unsigned ohi = (unsigned)__builtin_amdgcn_mov_dpp((int)hi, CTRL, 0xF, 0xF, true);
  return umin64(k, ((u64)ohi << 32) | olo);
}
static __device__ __forceinline__ u64 x16_min64(u64 k) {
  unsigned lo = (unsigned)k, hi = (unsigned)(k >> 32);
#if __has_builtin(__builtin_amdgcn_permlane16_swap)
  auto rlo = __builtin_amdgcn_permlane16_swap(lo, lo, false, false);
  auto rhi = __builtin_amdgcn_permlane16_swap(hi, hi, false, false);
  u64 a = ((u64)rhi[0] << 32) | rlo[0];
  u64 b = ((u64)rhi[1] << 32) | rlo[1];
  return umin64(k, umin64(a, b));
#else
  unsigned olo = (unsigned)__builtin_amdgcn_ds_swizzle((int)lo, 0x401F);
  unsigned ohi = (unsigned)__builtin_amdgcn_ds_swizzle((int)hi, 0x401F);
  return umin64(k, ((u64)ohi << 32) | olo);
#endif
}
static __device__ __forceinline__ u64 x32_min64(u64 k) {
  unsigned lo = (unsigned)k, hi = (unsigned)(k >> 32);
#if __has_builtin(__builtin_amdgcn_permlane32_swap)
  auto rlo = __builtin_amdgcn_permlane32_swap(lo, lo, false, false);
  auto rhi = __builtin_amdgcn_permlane32_swap(hi, hi, false, false);
  u64 a = ((u64)rhi[0] << 32) | rlo[0];
  u64 b = ((u64)rhi[1] << 32) | rlo[1];
  return umin64(k, umin64(a, b));
#else
  unsigned olo = (unsigned)__shfl_xor((int)lo, 32, 64);
  unsigned ohi = (unsigned)__shfl_xor((int)hi, 32, 64);
  return umin64(k, ((u64)ohi << 32) | olo);
#endif
}
static __device__ __forceinline__ u64 wave_min_u64(u64 k) {
  k = dpp_min64<0xB1>(k);
  k = dpp_min64<0x4E>(k);
  k = dpp_min64<0x141>(k);
  k = dpp_min64<0x140>(k);
  k = x16_min64(k);
  k = x32_min64(k);
  return k;  // wave-uniform
}

#define FOR16(M) M(0) M(1) M(2) M(3) M(4) M(5) M(6) M(7) \
                 M(8) M(9) M(10) M(11) M(12) M(13) M(14) M(15)

// Lane's 32 target columns in NAMED registers, as float2 pairs.
#define LOADP(h) \
  v2f TX##h, TY##h, TZ##h, TQ##h; \
  { float x0 = tb[6*h+0], y0 = tb[6*h+1], z0 = tb[6*h+2]; \
    float x1 = tb[6*h+3], y1 = tb[6*h+4], z1 = tb[6*h+5]; \
    TX##h = (v2f){x0, x1}; TY##h = (v2f){y0, y1}; TZ##h = (v2f){z0, z1}; \
    TQ##h = (v2f){x0*x0 + y0*y0 + z0*z0, x1*x1 + y1*y1 + z1*z1}; }

// ---------- phase 1: exact per-row sorted top-32, targets in registers ----------
#define DISTK(h) u64 KA##h, KB##h; { \
  v2f dot = __builtin_elementwise_fma(TX##h, Xv, \
              __builtin_elementwise_fma(TY##h, Yv, TZ##h * Zv)); \
  v2f dd  = __builtin_elementwise_fma(m2v, dot, TQ##h); \
  v2f d2  = Qv + dd; \
  float c0 = fmaxf(d2.x, 1e-12f), c1 = fmaxf(d2.y, 1e-12f); \
  KA##h = ((u64)(u32)__float_as_int(c0) << 32) | (u32)(base + 2*(h)); \
  KB##h = ((u64)(u32)__float_as_int(c1) << 32) | (u32)(base + 2*(h) + 1); }

#define ZCASE(h) \
  case (2*(h)):     KA##h = own ? ~0ULL : KA##h; break; \
  case (2*(h) + 1): KB##h = own ? ~0ULL : KB##h; break;

__global__ __launch_bounds__(64, 2) void emd_topk_kernel(
    const float* __restrict__ pred, const float* __restrict__ target,
    u64* __restrict__ lists) {
  const int blk = blockIdx.x;
  const int b = blk / (NPTS / RPB);
  const int r0 = (blk % (NPTS / RPB)) * RPB;
  const int lane = threadIdx.x;
  const float* p = pred + (size_t)b * NPTS * 3;
  const float* t = target + (size_t)b * NPTS * 3;

  const float* tb = t + (size_t)lane * 32 * 3;
  FOR16(LOADP)
  const int base = lane << 5;
  const v2f m2v = {-2.f, -2.f};

  for (int rr = 0; rr < RPB; ++rr) {
    const int i = r0 + rr;
    const float X = p[3 * i], Y = p[3 * i + 1], Z = p[3 * i + 2];
    const float Q = fmaf(X, X, fmaf(Y, Y, Z * Z));
    const v2f Xv = {X, X}, Yv = {Y, Y}, Zv = {Z, Z}, Qv = {Q, Q};
    FOR16(DISTK)

    u64* out = lists + ((size_t)b * NPTS + i) * TOPK;
    for (int e = 0; e < TOPK; ++e) {
      u64 m;
      {
        u64 a0 = umin64(KA0, KB0),   a1 = umin64(KA1, KB1);
        u64 a2 = umin64(KA2, KB2),   a3 = umin64(KA3, KB3);
        u64 a4 = umin64(KA4, KB4),   a5 = umin64(KA5, KB5);
        u64 a6 = umin64(KA6, KB6),   a7 = umin64(KA7, KB7);
        u64 a8 = umin64(KA8, KB8),   a9 = umin64(KA9, KB9);
        u64 a10 = umin64(KA10, KB10), a11 = umin64(KA11, KB11);
        u64 a12 = umin64(KA12, KB12), a13 = umin64(KA13, KB13);
        u64 a14 = umin64(KA14, KB14), a15 = umin64(KA15, KB15);
        u64 b0 = umin64(a0, a1), b1 = umin64(a2, a3);
        u64 b2 = umin64(a4, a5), b3 = umin64(a6, a7);
        u64 b4 = umin64(a8, a9), b5 = umin64(a10, a11);
        u64 b6 = umin64(a12, a13), b7 = umin64(a14, a15);
        u64 c0 = umin64(b0, b1), c1 = umin64(b2, b3);
        u64 c2 = umin64(b4, b5), c3 = umin64(b6, b7);
        m = umin64(umin64(c0, c1), umin64(c2, c3));
      }
      m = wave_min_u64(m);
      if (lane == 0) out[e] = m;
      const u32 col = (u32)m & (u32)(NPTS - 1);     // wave-uniform
      const bool own = (lane == (int)(col >> 5));
      switch (col & 31u) { FOR16(ZCASE) }
    }
  }
}

// ---------- phase 2: sequential greedy, stale-probe pipelined ----------
// Probe for row r (ds_bpermute of candidates' used-bits) is issued 4 rows
// early; exactness restored by comparing candidates against the last 3
// winners: U_r = U_{r-4} + {w_{r-1}, w_{r-2}, w_{r-3}}.
#define FALLBACK(ROW) { \
    float X = p[3 * (ROW)], Y = p[3 * (ROW) + 1], Z = p[3 * (ROW) + 2]; \
    float Q = fmaf(X, X, fmaf(Y, Y, Z * Z)); \
    u64 best = ~0ULL; \
    for (int k = 0; k < 32; ++k) { \
      float4 c4 = tt[(k << 6) | (lane ^ k)]; \
      float dot = fmaf(c4.x, X, fmaf(c4.y, Y, c4.z * Z)); \
      float d2 = Q + fmaf(-2.f, dot, c4.w); \
      d2 = fmaxf(d2, 1e-12f); \
      u64 key = ((u64)(u32)__float_as_int(d2) << 32) | (u32)((lane << 5) + k); \
      if ((usedmask >> k) & 1u) key = ~0ULL; \
      best = umin64(best, key); \
    } \
    u64 m = wave_min_u64(best); \
    u32 cs = (u32)m & (u32)(NPTS - 1); \
    usedmask |= (lane == (int)(cs >> 5)) ? (1u << (cs & 31u)) : 0u; \
    sum += sqrtf(__uint_as_float((u32)(m >> 32))); \
    w3 = w2; w2 = w1; w1 = cs; \
  }

#define RESOLVE(CR, PR, ROW) { \
    u32 cc = (u32)(CR) & (u32)(NPTS - 1); \
    u64 freebl = __ballot((((PR) >> (cc & 31u)) & 1u) == 0u); \
    u64 badbl  = __ballot(cc == w1) | __ballot(cc == w2) | __ballot(cc == w3); \
    u64 bl = freebl & ~badbl & 0xFFFFFFFFull; \
    if (bl != 0) { \
      int R = __ffsll(bl) - 1; \
      u32 mlo = (u32)__builtin_amdgcn_readlane((int)(u32)(CR), R); \
      u32 mhi = (u32)__builtin_amdgcn_readlane((int)(u32)((CR) >> 32), R); \
      u32 cs = mlo & (u32)(NPTS - 1); \
      usedmask |= (lane == (int)(cs >> 5)) ? (1u << (cs & 31u)) : 0u; \
      sum += sqrtf(__uint_as_float(mhi)); \
      w3 = w2; w2 = w1; w1 = cs; \
    } else { \
      FALLBACK(ROW) \
    } }

#define ISSUE(PR, CS) { \
    u32 qc = (u32)(CS) & (u32)(NPTS - 1); \
    PR = (u32)__builtin_amdgcn_ds_bpermute((int)((qc >> 5) << 2), (int)usedmask); }

#define RELOAD(CR, ROW) { \
    int rr_ = (ROW) < NPTS ? (ROW) : (NPTS - 1); \
    CR = L[(size_t)rr_ * TOPK + li]; }

#define STEP(J, CR, PR, CN, I) \
    RESOLVE(CR, PR, (I) + (J)) \
    ISSUE(PR, CN) \
    RELOAD(CR, (I) + (J) + 16)

__global__ __launch_bounds__(64, 1) void emd_seq_kernel(
    const float* __restrict__ pred, const float* __restrict__ target,
    const u64* __restrict__ lists, float* __restrict__ batch_sums) {
  const int b = blockIdx.x, lane = threadIdx.x;
  const float* p = pred + (size_t)b * NPTS * 3;
  const float* t = target + (size_t)b * NPTS * 3;

  // Fallback targets: column c at tt[((c&31)<<6) | ((c>>5) ^ (c&31))]
  // (XOR swizzle: staging writes spread 4-way instead of 32-way).
  __shared__ float4 tt[NPTS];
  for (int j = lane; j < NPTS; j += 64) {
    float x = t[3 * j], y = t[3 * j + 1], z = t[3 * j + 2];
    tt[((j & 31) << 6) | ((j >> 5) ^ (j & 31))] =
        make_float4(x, y, z, fmaf(x, x, fmaf(y, y, z * z)));
  }
  __syncthreads();

  const u64* L = lists + (size_t)b * NPTS * TOPK;
  const int li = lane & (TOPK - 1);
  u32 usedmask = 0;
  u32 w1 = 0xFFFFFFFFu, w2 = 0xFFFFFFFFu, w3 = 0xFFFFFFFFu;
  float sum = 0.f;

  // 16-deep candidate prefetch; 4-deep probe pipeline.
  u64 C0 = L[0 * TOPK + li],  C1 = L[1 * TOPK + li];
  u64 C2 = L[2 * TOPK + li],  C3 = L[3 * TOPK + li];
  u64 C4 = L[4 * TOPK + li],  C5 = L[5 * TOPK + li];
  u64 C6 = L[6 * TOPK + li],  C7 = L[7 * TOPK + li];
  u64 C8 = L[8 * TOPK + li],  C9 = L[9 * TOPK + li];
  u64 C10 = L[10 * TOPK + li], C11 = L[11 * TOPK + li];
  u64 C12 = L[12 * TOPK + li], C13 = L[13 * TOPK + li];
  u64 C14 = L[14 * TOPK + li], C15 = L[15 * TOPK + li];
  u32 P0, P1, P2, P3;
  ISSUE(P0, C0) ISSUE(P1, C1) ISSUE(P2, C2) ISSUE(P3, C3)

  for (int i = 0; i < NPTS; i += 16) {
    STEP(0,  C0,  P0, C4,  i)
    STEP(1,  C1,  P1, C5,  i)
    STEP(2,  C2,  P2, C6,  i)
    STEP(3,  C3,  P3, C7,  i)
    STEP(4,  C4,  P0, C8,  i)
    STEP(5,  C5,  P1, C9,  i)
    STEP(6,  C6,  P2, C10, i)
    STEP(7,  C7,  P3, C11, i)
    STEP(8,  C8,  P0, C12, i)
    STEP(9,  C9,  P1, C13, i)
    STEP(10, C10, P2, C14, i)
    STEP(11, C11, P3, C15, i)
    STEP(12, C12, P0, C0,  i)
    STEP(13, C13, P1, C1,  i)
    STEP(14, C14, P2, C2,  i)
    STEP(15, C15, P3, C3,  i)
  }
  if (lane == 0) batch_sums[b] = sum;
}

// ---------- legacy single-kernel path (round-5, proven; ws-too-small) ----------
#define DECLRU(h) v2u RU##h;
#define DIST(h) { \
  v2f dot = __builtin_elementwise_fma(TX##h, Xv, \
              __builtin_elementwise_fma(TY##h, Yv, TZ##h * Zv)); \
  v2f dd  = __builtin_elementwise_fma(m2v, dot, TQ##h); \
  v2f d2  = Qv + dd; \
  RU##h = (v2u){(u32)__float_as_int(d2.x), (u32)__float_as_int(d2.y)}; }
#define TOUR(h, c) { \
  u32 u0 = RU##h.x | sext_bit(usedmask, 2*h); \
  u32 u1 = RU##h.y | sext_bit(usedmask, 2*h + 1); \
  u32 pu = umin32(u0, u1); \
  u32 pk = (u1 < u0) ? (u32)(2*h + 1) : (u32)(2*h); \
  if (pu < bc##c) { bc##c = pu; kc##c = pk; } }

__global__ __launch_bounds__(64, 1) void emd_greedy_kernel(
    const float* __restrict__ pred, const float* __restrict__ target,
    float* __restrict__ batch_sums) {
  const int b = blockIdx.x, lane = threadIdx.x;
  const float* p = pred + (size_t)b * NPTS * 3;
  const float* t = target + (size_t)b * NPTS * 3;
  __shared__ float4 pp[NPTS + 2];
  for (int i = lane; i < NPTS; i += 64) {
    float x = p[3 * i], y = p[3 * i + 1], z = p[3 * i + 2];
    pp[i] = make_float4(x, y, z, x * x + y * y + z * z);
  }
  if (lane < 2) pp[NPTS + lane] = make_float4(0.f, 0.f, 0.f, 0.f);
  const float* tb = t + (size_t)lane * 32 * 3;
  FOR16(LOADP)
  FOR16(DECLRU)
  u32 usedmask = 0;
  float sum = 0.f;
  __syncthreads();
  const v2f m2v = {-2.f, -2.f};
  v2f Xv, Yv, Zv, Qv;
  {
    float4 A = pp[0];
    Xv = (v2f){A.x, A.x}; Yv = (v2f){A.y, A.y};
    Zv = (v2f){A.z, A.z}; Qv = (v2f){A.w, A.w};
    FOR16(DIST)
  }
  for (int i = 0; i < NPTS; ++i) {
    float4 An = pp[i + 1];
    u32 bc0 = ~0u, bc1 = ~0u, bc2 = ~0u, bc3 = ~0u;
    u32 kc0 = 0, kc1 = 0, kc2 = 0, kc3 = 0;
    TOUR(0, 0)  TOUR(1, 0)  TOUR(2, 0)  TOUR(3, 0)
    TOUR(4, 1)  TOUR(5, 1)  TOUR(6, 1)  TOUR(7, 1)
    TOUR(8, 2)  TOUR(9, 2)  TOUR(10, 2) TOUR(11, 2)
    TOUR(12, 3) TOUR(13, 3) TOUR(14, 3) TOUR(15, 3)
    bool s01 = bc1 < bc0; u32 v01 = s01 ? bc1 : bc0; u32 i01 = s01 ? kc1 : kc0;
    bool s23 = bc3 < bc2; u32 v23 = s23 ? bc3 : bc2; u32 i23 = s23 ? kc3 : kc2;
    bool sf  = v23 < v01; u32 bu  = sf ? v23 : v01; u32 bk  = sf ? i23 : i01;
    Xv = (v2f){An.x, An.x}; Yv = (v2f){An.y, An.y};
    Zv = (v2f){An.z, An.z}; Qv = (v2f){An.w, An.w};
    FOR16(DIST)
    u32 m = bu;
    m = dpp_min<0xB1>(m); m = dpp_min<0x4E>(m);
    m = dpp_min<0x141>(m); m = dpp_min<0x140>(m);
    m = x16_min(m); m = x32_min(m);
    u64 mk = __ballot(bu == m);
    int first = __ffsll(mk) - 1;
    usedmask |= (lane == first) ? (1u << bk) : 0u;
    sum += sqrtf(fmaxf(__uint_as_float(m), 1e-12f));
  }
  if (lane == 0) batch_sums[b] = sum;
}

// ---------- finalize ----------
__global__ void emd_finalize_kernel(const float* __restrict__ batch_sums,
                                    float* __restrict__ out, int B) {
  float acc = 0.f;
  for (int b = 0; b < B; ++b) acc += batch_sums[b] / (float)NPTS;
  out[0] = acc / (float)B;
}

extern "C" void kernel_launch(void* const* d_in, const int* in_sizes, int n_in,
                              void* d_out, int out_size, void* d_ws, size_t ws_size,
                              hipStream_t stream) {
  const float* pred   = (const float*)d_in[0];
  const float* target = (const float*)d_in[1];
  float* out = (float*)d_out;
  const int B = in_sizes[0] / (NPTS * 3);

  const size_t need = 256 + (size_t)B * NPTS * TOPK * sizeof(u64);
  if (ws_size >= need) {
    float* bs = (float*)d_ws;
    u64* lists = (u64*)((char*)d_ws + 256);
    emd_topk_kernel<<<B * (NPTS / RPB), 64, 0, stream>>>(pred, target, lists);
    emd_seq_kernel<<<B, 64, 0, stream>>>(pred, target, lists, bs);
    emd_finalize_kernel<<<1, 1, 0, stream>>>(bs, out, B);
  } else {
    float* bs = (float*)d_ws;
    emd_greedy_kernel<<<B, 64, 0, stream>>>(pred, target, bs);
    emd_finalize_kernel<<<1, 1, 0, stream>>>(bs, out, B);
  }
}